// Round 1
// baseline (8456.895 us; speedup 1.0000x reference)
//
#include <hip/hip_runtime.h>
#include <math.h>

#define NB   32      // batch
#define FDIM 2048    // image feature dim
#define VV   12000   // vocab
#define DWW  300     // word embedding dim
#define HH   512     // hidden
#define KW   3       // beam width
#define TDEC 32      // decode steps
#define SEQ  33      // teacher steps (T+1)
#define NK   96      // NB*KW
#define G4   2048    // 4*HH
#define START_ID 1
#define END_ID   2
#define NEGV (-1e9f)
#define NROWS (NK*SEQ)   // 3168
#define NCB   94         // final GEMM col blocks: ceil(12000/128)

__device__ __forceinline__ float sigf(float x){ return 1.0f/(1.0f+expf(-x)); }

// insert (v,i) into sorted-desc top3 with tie-break: equal value -> smaller index wins
__device__ __forceinline__ void ins3(float v, int i, float tv[3], int ti[3]){
  if (v > tv[0] || (v == tv[0] && i < ti[0])){
    tv[2]=tv[1]; ti[2]=ti[1]; tv[1]=tv[0]; ti[1]=ti[0]; tv[0]=v; ti[0]=i;
  } else if (v > tv[1] || (v == tv[1] && i < ti[1])){
    tv[2]=tv[1]; ti[2]=ti[1]; tv[1]=v; ti[1]=i;
  } else if (v > tv[2] || (v == tv[2] && i < ti[2])){
    tv[2]=v; ti[2]=i;
  }
}

// ---------------- P_img = img @ Wx[300:,:] (+ b_lstm in reduce) ----------------
// grid (16 colblk, 16 fblk), block 128. parts[fb][32][2048]
__global__ __launch_bounds__(128) void k_pimg(const float* __restrict__ img,
                                              const float* __restrict__ Wx,
                                              float* __restrict__ parts)
{
  int colb = blockIdx.x, fb = blockIdx.y, tid = threadIdx.x;
  int col = colb*128 + tid;
  int f0 = fb*128;
  __shared__ float s_img[32][128];
  for (int r=0;r<32;r++) s_img[r][tid] = img[r*FDIM + f0 + tid];
  __syncthreads();
  float acc[32];
  #pragma unroll
  for (int r=0;r<32;r++) acc[r]=0.f;
  for (int f2=0; f2<128; ++f2){
    float w = Wx[(size_t)(DWW + f0 + f2)*G4 + col];
    #pragma unroll
    for (int r=0;r<32;r++) acc[r] += w * s_img[r][f2];
  }
  #pragma unroll
  for (int r=0;r<32;r++) parts[(size_t)fb*(32*G4) + r*G4 + col] = acc[r];
}

// grid 256, block 256: P[b][j] = b_lstm[j] + sum_fb parts
__global__ __launch_bounds__(256) void k_preduce(const float* __restrict__ parts,
                                                 const float* __restrict__ b_lstm,
                                                 float* __restrict__ P)
{
  int i = blockIdx.x*256 + threadIdx.x;  // < 65536
  float s = b_lstm[i & (G4-1)];
  for (int fb=0; fb<16; ++fb) s += parts[(size_t)fb*(32*G4) + i];
  P[i] = s;
}

// ---------------- beam state init ----------------
__global__ __launch_bounds__(512) void k_init(float* h, float* c, float* beam_lp,
                                              int* prev, int* finished, int* lengths, int* ids)
{
  int n = blockIdx.x, m = threadIdx.x;
  h[(size_t)n*HH+m]=0.f; c[(size_t)n*HH+m]=0.f;
  if (m==0){ beam_lp[n] = (n%KW==0)?0.f:NEGV; prev[n]=START_ID; finished[n]=0; lengths[n]=0; }
  if (m<TDEC) ids[n*TDEC+m]=0;
}

__global__ __launch_bounds__(512) void k_treset(float* h, float* c)
{
  int n = blockIdx.x, m = threadIdx.x;
  h[(size_t)n*HH+m]=0.f; c[(size_t)n*HH+m]=0.f;
}

// ---------------- LSTM pre-activation GEMM (K-split partials) ----------------
// z[96 x 2048] = X[96 x 812] @ [Wx[:300]; Wh],  X = [E[word], h]
// grid (32 colblk of 64, 8 ksplit), block 256. zp[p][96][2048]
__global__ __launch_bounds__(256) void k_zgemm(
    const float* __restrict__ E, const float* __restrict__ Wx, const float* __restrict__ Wh,
    const float* __restrict__ h, const int* __restrict__ prev, const int* __restrict__ ids,
    float* __restrict__ zp, int t, int teacher)
{
  int bx = blockIdx.x, p = blockIdx.y, tid = threadIdx.x;
  int col0 = bx*64;
  int ks = p*104;
  int ke = ks+104 < 812 ? ks+104 : 812;
  __shared__ float sA[96*17];
  __shared__ float sB[16*64];
  int tx = tid & 15, ty = tid >> 4;   // cols: col0+tx*4..+3 ; rows: ty + rr*16
  float4 acc[6];
  #pragma unroll
  for (int r=0;r<6;r++) acc[r] = make_float4(0.f,0.f,0.f,0.f);

  for (int k0=ks; k0<ke; k0+=16){
    int bk = ke-k0; if (bk>16) bk=16;
    for (int i=tid; i<96*16; i+=256){
      int n = i>>4, kk = i&15;
      float v = 0.f;
      if (kk < bk){
        int kg = k0 + kk;
        if (kg < DWW){
          int w = teacher ? (t==0 ? START_ID : ids[n*TDEC + (t-1)]) : prev[n];
          v = E[(size_t)w*DWW + kg];
        } else {
          v = h[(size_t)n*HH + (kg-DWW)];
        }
      }
      sA[n*17+kk] = v;
    }
    for (int i=tid; i<16*64; i+=256){
      int kk = i>>6, cc = i&63;
      float v = 0.f;
      if (kk < bk){
        int kg = k0+kk;
        v = (kg<DWW) ? Wx[(size_t)kg*G4 + col0+cc] : Wh[(size_t)(kg-DWW)*G4 + col0+cc];
      }
      sB[i] = v;
    }
    __syncthreads();
    #pragma unroll
    for (int kk=0; kk<16; ++kk){
      float4 bv = *(const float4*)&sB[kk*64 + tx*4];
      #pragma unroll
      for (int rr=0;rr<6;rr++){
        float a = sA[(ty + rr*16)*17 + kk];
        acc[rr].x += a*bv.x; acc[rr].y += a*bv.y; acc[rr].z += a*bv.z; acc[rr].w += a*bv.w;
      }
    }
    __syncthreads();
  }
  float* zpp = zp + (size_t)p*NK*G4;
  #pragma unroll
  for (int rr=0;rr<6;rr++){
    int row = ty + rr*16;
    *(float4*)&zpp[(size_t)row*G4 + col0 + tx*4] = acc[rr];
  }
}

// ---------------- LSTM cell: reduce 8 partials + P, apply gates ----------------
// grid 96, block 512
__global__ __launch_bounds__(512) void k_cell(
    const float* __restrict__ zp, const float* __restrict__ P,
    float* __restrict__ h, float* __restrict__ c,
    float* __restrict__ h2, float* __restrict__ c2,
    const int* __restrict__ lengths, float* __restrict__ acts,
    int t, int teacher)
{
  int n = blockIdx.x, m = threadIdx.x;
  int bb = n/KW;
  const float* Pr = P + (size_t)bb*G4;
  float zi=Pr[m], zf=Pr[HH+m], zg=Pr[2*HH+m], zo=Pr[3*HH+m];
  for (int p=0;p<8;p++){
    const float* zz = zp + (size_t)p*NK*G4 + (size_t)n*G4;
    zi += zz[m]; zf += zz[HH+m]; zg += zz[2*HH+m]; zo += zz[3*HH+m];
  }
  float cold = c[(size_t)n*HH+m];
  float c2v = sigf(zf+1.0f)*cold + sigf(zi)*tanhf(zg);
  float h2v = sigf(zo)*tanhf(c2v);
  if (teacher){
    bool act = t < lengths[n];
    if (act){ h[(size_t)n*HH+m]=h2v; c[(size_t)n*HH+m]=c2v; }
    acts[((size_t)n*SEQ+t)*HH+m] = act ? h2v : 0.f;
  } else {
    h2[(size_t)n*HH+m]=h2v; c2[(size_t)n*HH+m]=c2v;
  }
}

// ---------------- decode logits GEMM: zp[p][96][12000] = h2 @ Wl (K-split 4) --------
// grid (188 colblk of 64, 4 ksplit), block 256
__global__ __launch_bounds__(256) void k_logitsp(
    const float* __restrict__ h2, const float* __restrict__ Wl, float* __restrict__ zp)
{
  int bx = blockIdx.x, p = blockIdx.y, tid = threadIdx.x;
  int col0 = bx*64;
  int ks = p*128, ke = ks+128;
  __shared__ float sA[96*17];
  __shared__ float sB[16*64];
  int tx = tid & 15, ty = tid >> 4;
  float4 acc[6];
  #pragma unroll
  for (int r=0;r<6;r++) acc[r] = make_float4(0.f,0.f,0.f,0.f);

  for (int k0=ks; k0<ke; k0+=16){
    for (int i=tid; i<96*16; i+=256){
      int n=i>>4, kk=i&15;
      sA[n*17+kk] = h2[(size_t)n*HH + k0+kk];
    }
    for (int i=tid; i<16*64; i+=256){
      int kk=i>>6, cc=i&63; int col=col0+cc;
      sB[i] = (col<VV) ? Wl[(size_t)(k0+kk)*VV + col] : 0.f;
    }
    __syncthreads();
    #pragma unroll
    for (int kk=0; kk<16; ++kk){
      float4 bv = *(const float4*)&sB[kk*64 + tx*4];
      #pragma unroll
      for (int rr=0;rr<6;rr++){
        float a = sA[(ty + rr*16)*17 + kk];
        acc[rr].x += a*bv.x; acc[rr].y += a*bv.y; acc[rr].z += a*bv.z; acc[rr].w += a*bv.w;
      }
    }
    __syncthreads();
  }
  float* zpp = zp + (size_t)p*NK*VV;
  int cg = col0 + tx*4;
  if (cg < VV){   // VV%4==0 -> float4 granularity is safe
    #pragma unroll
    for (int rr=0;rr<6;rr++){
      int row = ty + rr*16;
      *(float4*)&zpp[(size_t)row*VV + cg] = acc[rr];
    }
  }
}

// ---------------- beam select: reduce partials, logsumexp, top3, reorder ----------
// grid 32 (one per batch), block 256
__global__ __launch_bounds__(256) void k_select(
    const float* __restrict__ zp, const float* __restrict__ blog,
    float* __restrict__ zred,
    float* __restrict__ h, float* __restrict__ c,
    const float* __restrict__ h2, const float* __restrict__ c2,
    float* __restrict__ beam_lp, int* __restrict__ prev,
    int* __restrict__ finished, int* __restrict__ lengths,
    int* __restrict__ ids, int t)
{
  int b = blockIdx.x, tid = threadIdx.x;
  int lane = tid & 63, wid = tid >> 6;
  __shared__ float s_f[4];
  __shared__ float s_wv[4][3]; __shared__ int s_wi[4][3];
  __shared__ float s_topv[KW][3]; __shared__ int s_topi[KW][3];
  __shared__ float s_lse[KW];
  __shared__ int s_par[KW], s_word[KW];
  __shared__ int s_ids[KW][TDEC];

  const size_t PS = (size_t)NK*VV;
  for (int k=0;k<KW;k++){
    int n = b*KW+k;
    const float* z0 = zp + (size_t)n*VV;
    float* zr = zred + (size_t)n*VV;
    float lmax = -INFINITY;
    float tv[3]={-INFINITY,-INFINITY,-INFINITY};
    int   ti[3]={0x7fffffff,0x7fffffff,0x7fffffff};
    for (int i=tid;i<VV;i+=256){
      float v = blog[i] + z0[i] + z0[PS+i] + z0[2*PS+i] + z0[3*PS+i];
      zr[i] = v;
      lmax = fmaxf(lmax, v);
      ins3(v,i,tv,ti);
    }
    #pragma unroll
    for (int d=1;d<64;d<<=1) lmax = fmaxf(lmax, __shfl_xor(lmax,d));
    if (lane==0) s_f[wid]=lmax;
    __syncthreads();
    float rmax = fmaxf(fmaxf(s_f[0],s_f[1]),fmaxf(s_f[2],s_f[3]));
    __syncthreads();
    float lsum = 0.f;
    for (int i=tid;i<VV;i+=256) lsum += expf(zr[i]-rmax);
    #pragma unroll
    for (int d=1;d<64;d<<=1){
      lsum += __shfl_xor(lsum,d);
      float p0=__shfl_xor(tv[0],d), p1=__shfl_xor(tv[1],d), p2=__shfl_xor(tv[2],d);
      int   q0=__shfl_xor(ti[0],d), q1=__shfl_xor(ti[1],d), q2=__shfl_xor(ti[2],d);
      ins3(p0,q0,tv,ti); ins3(p1,q1,tv,ti); ins3(p2,q2,tv,ti);
    }
    if (lane==0){
      s_f[wid]=lsum;
      s_wv[wid][0]=tv[0]; s_wv[wid][1]=tv[1]; s_wv[wid][2]=tv[2];
      s_wi[wid][0]=ti[0]; s_wi[wid][1]=ti[1]; s_wi[wid][2]=ti[2];
    }
    __syncthreads();
    if (tid==0){
      float rsum = s_f[0]+s_f[1]+s_f[2]+s_f[3];
      float mv[3]={-INFINITY,-INFINITY,-INFINITY};
      int   mi[3]={0x7fffffff,0x7fffffff,0x7fffffff};
      for (int w2=0; w2<4; ++w2)
        for (int j=0;j<3;j++) ins3(s_wv[w2][j], s_wi[w2][j], mv, mi);
      s_lse[k] = rmax + logf(rsum);
      for (int j=0;j<3;j++){ s_topv[k][j]=mv[j]; s_topi[k][j]=mi[j]; }
    }
    __syncthreads();
  }

  if (tid==0){
    float cv[3]={-INFINITY,-INFINITY,-INFINITY};
    int   cf[3]={0x7fffffff,0x7fffffff,0x7fffffff};
    for (int k=0;k<KW;k++){
      int n=b*KW+k;
      if (finished[n]){
        ins3(beam_lp[n], k*VV+END_ID, cv, cf);   // finished beam emits END with lp 0
      } else {
        float blp = beam_lp[n], lse = s_lse[k];
        for (int j=0;j<3;j++)
          ins3(blp + (s_topv[k][j] - lse), k*VV + s_topi[k][j], cv, cf);
      }
    }
    int fin_old[3], len_old[3];
    for (int j=0;j<3;j++){ fin_old[j]=finished[b*KW+j]; len_old[j]=lengths[b*KW+j]; }
    for (int kp=0;kp<KW;kp++){
      int par = cf[kp]/VV, word = cf[kp]-par*VV;
      s_par[kp]=par; s_word[kp]=word;
      beam_lp[b*KW+kp]=cv[kp];
      prev[b*KW+kp]=word;
      int fp = fin_old[par];
      lengths[b*KW+kp] = fp ? len_old[par] : (len_old[par]+1);
      finished[b*KW+kp] = fp | (word==END_ID);
    }
  }
  __syncthreads();
  for (int i=tid;i<KW*HH;i+=256){
    int slot=i/HH, m=i%HH;
    h[(size_t)(b*KW+slot)*HH+m] = h2[(size_t)(b*KW+s_par[slot])*HH+m];
    c[(size_t)(b*KW+slot)*HH+m] = c2[(size_t)(b*KW+s_par[slot])*HH+m];
  }
  if (tid < KW*TDEC){
    int slot=tid/TDEC, tt=tid%TDEC;
    s_ids[slot][tt] = ids[(b*KW+s_par[slot])*TDEC+tt];
  }
  __syncthreads();
  if (tid < KW*TDEC){
    int slot=tid/TDEC, tt=tid%TDEC;
    ids[(b*KW+slot)*TDEC+tt] = (tt==t) ? s_word[slot] : s_ids[slot][tt];
  }
}

// ---------------- final logits GEMM [3168x512]@[512x12000] + bias + argmax partials --
// grid (94, 50), block 256. BM=64, BN=128, thread tile 8r x 4c
__global__ __launch_bounds__(256) void k_final(
    const float* __restrict__ acts, const float* __restrict__ Wl,
    const float* __restrict__ blog, float* __restrict__ out, float* __restrict__ argp)
{
  int bx=blockIdx.x, by=blockIdx.y, tid=threadIdx.x;
  int col0 = bx*128, row0 = by*64;
  __shared__ float sA[64*17];
  __shared__ float sB[16*128];
  __shared__ float s_amv[64][33];
  __shared__ int   s_ami[64][33];
  int tx = tid & 31, ty = tid >> 5;   // cols: col0+tx*4 ; rows: ty + rr*8
  int colg = col0 + tx*4;
  bool cval = colg < VV;              // VV%4==0 and 12000-11904=96 -> full-float4 granularity
  float4 acc[8];
  #pragma unroll
  for (int r=0;r<8;r++) acc[r]=make_float4(0.f,0.f,0.f,0.f);

  for (int k0=0;k0<HH;k0+=16){
    for (int i=tid;i<64*16;i+=256){
      int r=i>>4, kk=i&15; int row=row0+r;
      sA[r*17+kk] = (row < NROWS) ? acts[(size_t)row*HH + k0+kk] : 0.f;
    }
    for (int i=tid;i<16*128;i+=256){
      int kk=i>>7, cc=i&127; int col=col0+cc;
      sB[i] = (col<VV) ? Wl[(size_t)(k0+kk)*VV + col] : 0.f;
    }
    __syncthreads();
    #pragma unroll
    for (int kk=0;kk<16;++kk){
      float4 bv = *(const float4*)&sB[kk*128 + tx*4];
      #pragma unroll
      for (int rr=0;rr<8;rr++){
        float a = sA[(ty + rr*8)*17 + kk];
        acc[rr].x += a*bv.x; acc[rr].y += a*bv.y; acc[rr].z += a*bv.z; acc[rr].w += a*bv.w;
      }
    }
    __syncthreads();
  }

  float4 b4 = make_float4(0.f,0.f,0.f,0.f);
  if (cval) b4 = *(const float4*)&blog[colg];
  #pragma unroll
  for (int rr=0;rr<8;rr++){
    int row_l = ty + rr*8;
    int row = row0 + row_l;
    float bv=-INFINITY; int bi=0x7fffffff;
    if (cval){
      acc[rr].x += b4.x; acc[rr].y += b4.y; acc[rr].z += b4.z; acc[rr].w += b4.w;
      if (row < NROWS) *(float4*)&out[(size_t)row*VV + colg] = acc[rr];
      bv = acc[rr].x; bi = colg;
      if (acc[rr].y > bv){ bv=acc[rr].y; bi=colg+1; }
      if (acc[rr].z > bv){ bv=acc[rr].z; bi=colg+2; }
      if (acc[rr].w > bv){ bv=acc[rr].w; bi=colg+3; }
    }
    s_amv[row_l][tx]=bv; s_ami[row_l][tx]=bi;
  }
  __syncthreads();
  if (tid < 64){
    int row = row0 + tid;
    if (row < NROWS){
      float bv=s_amv[tid][0]; int bi=s_ami[tid][0];
      for (int j=1;j<32;j++){
        float v=s_amv[tid][j]; int i2=s_ami[tid][j];
        if (v>bv || (v==bv && i2<bi)){ bv=v; bi=i2; }
      }
      argp[((size_t)row*NCB + bx)*2]   = bv;
      argp[((size_t)row*NCB + bx)*2+1] = (float)bi;
    }
  }
}

// grid 13, block 256: reduce 94 partials per row, write argmax as float
__global__ __launch_bounds__(256) void k_amax(const float* __restrict__ argp,
                                              float* __restrict__ outb)
{
  int rg = blockIdx.x*256 + threadIdx.x;
  if (rg >= NROWS) return;
  float bv = argp[(size_t)rg*NCB*2];
  int   bi = (int)argp[(size_t)rg*NCB*2+1];
  for (int p2=1;p2<NCB;p2++){
    float v = argp[((size_t)rg*NCB+p2)*2];
    int  i2 = (int)argp[((size_t)rg*NCB+p2)*2+1];
    if (v>bv || (v==bv && i2<bi)){ bv=v; bi=i2; }
  }
  outb[rg] = (float)bi;
}

extern "C" void kernel_launch(void* const* d_in, const int* in_sizes, int n_in,
                              void* d_out, int out_size, void* d_ws, size_t ws_size,
                              hipStream_t stream) {
  (void)in_sizes; (void)n_in; (void)out_size; (void)ws_size;
  const float* img  = (const float*)d_in[0];
  const float* E    = (const float*)d_in[1];
  const float* Wx   = (const float*)d_in[2];
  const float* Wh   = (const float*)d_in[3];
  const float* bls  = (const float*)d_in[4];   // b_lstm
  const float* Wl   = (const float*)d_in[5];
  const float* blog = (const float*)d_in[6];   // b_logits
  float* out = (float*)d_out;

  float* ws = (float*)d_ws;
  size_t o = 0;
  float* P    = ws + o; o += (size_t)NB*G4;            // 65536
  float* h    = ws + o; o += (size_t)NK*HH;
  float* c    = ws + o; o += (size_t)NK*HH;
  float* h2   = ws + o; o += (size_t)NK*HH;
  float* c2   = ws + o; o += (size_t)NK*HH;
  float* zpL  = ws + o; o += (size_t)8*NK*G4;          // LSTM GEMM partials
  float* zpG  = ws + o; o += (size_t)4*NK*VV;          // logits GEMM partials
  float* parts = zpG;                                   // alias: only used before decode
  float* zred = ws + o; o += (size_t)NK*VV;
  float* beam_lp = ws + o; o += 128;
  float* acts = ws + o; o += (size_t)NK*SEQ*HH;
  float* argp = ws + o; o += (size_t)NROWS*NCB*2;
  int* prev     = (int*)(ws + o); o += 128;
  int* finished = (int*)(ws + o); o += 128;
  int* lengths  = (int*)(ws + o); o += 128;
  int* ids      = (int*)(ws + o); o += NK*TDEC;

  // precompute P = b_lstm + img @ Wx[300:,:]
  k_pimg<<<dim3(16,16),128,0,stream>>>(img, Wx, parts);
  k_preduce<<<256,256,0,stream>>>(parts, bls, P);
  k_init<<<NK,HH,0,stream>>>(h,c,beam_lp,prev,finished,lengths,ids);

  // beam-search decode
  for (int t=0;t<TDEC;t++){
    k_zgemm<<<dim3(32,8),256,0,stream>>>(E,Wx,Wh,h,prev,ids,zpL,t,0);
    k_cell<<<NK,HH,0,stream>>>(zpL,P,h,c,h2,c2,lengths,acts,t,0);
    k_logitsp<<<dim3(188,4),256,0,stream>>>(h2,Wl,zpG);
    k_select<<<NB,256,0,stream>>>(zpG,blog,zred,h,c,h2,c2,beam_lp,prev,finished,lengths,ids,t);
  }

  // teacher-forced re-run
  k_treset<<<NK,HH,0,stream>>>(h,c);
  for (int t=0;t<SEQ;t++){
    k_zgemm<<<dim3(32,8),256,0,stream>>>(E,Wx,Wh,h,prev,ids,zpL,t,1);
    k_cell<<<NK,HH,0,stream>>>(zpL,P,h,c,h2,c2,lengths,acts,t,1);
  }

  // final logits + argmax
  k_final<<<dim3(NCB,50),256,0,stream>>>(acts,Wl,blog,out,argp);
  k_amax<<<13,256,0,stream>>>(argp, out + (size_t)NROWS*VV);
}

// Round 2
// 4783.829 us; speedup vs baseline: 1.7678x; 1.7678x over previous
//
#include <hip/hip_runtime.h>
#include <math.h>

#define NB   32      // batch
#define FDIM 2048    // image feature dim
#define VV   12000   // vocab
#define DWW  300     // word embedding dim
#define HH   512     // hidden
#define KW   3       // beam width
#define TDEC 32      // decode steps
#define SEQ  33      // teacher steps (T+1)
#define NK   96      // NB*KW
#define G4   2048    // 4*HH
#define START_ID 1
#define END_ID   2
#define NEGV (-1e9f)
#define NROWS (NK*SEQ)   // 3168
#define NCB   94         // final GEMM col blocks (128 cols each)
#define NLB   188        // logitsA col blocks (64 cols each)
#define INTMX 0x7fffffff

typedef float f4v __attribute__((ext_vector_type(4)));
__device__ __forceinline__ void nt_store4(float* p, float4 v){
  f4v t; t.x=v.x; t.y=v.y; t.z=v.z; t.w=v.w;
  __builtin_nontemporal_store(t, (f4v*)p);
}

__device__ __forceinline__ float sigf(float x){ return 1.0f/(1.0f+expf(-x)); }

// insert (v,i) into sorted-desc top3; tie -> smaller index wins
__device__ __forceinline__ void ins3(float v, int i, float tv[3], int ti[3]){
  if (v > tv[0] || (v == tv[0] && i < ti[0])){
    tv[2]=tv[1]; ti[2]=ti[1]; tv[1]=tv[0]; ti[1]=ti[0]; tv[0]=v; ti[0]=i;
  } else if (v > tv[1] || (v == tv[1] && i < ti[1])){
    tv[2]=tv[1]; ti[2]=ti[1]; tv[1]=v; ti[1]=i;
  } else if (v > tv[2] || (v == tv[2] && i < ti[2])){
    tv[2]=v; ti[2]=i;
  }
}

// ---------------- P_img = img @ Wx[300:,:] ----------------
__global__ __launch_bounds__(128) void k_pimg(const float* __restrict__ img,
                                              const float* __restrict__ Wx,
                                              float* __restrict__ parts)
{
  int colb = blockIdx.x, fb = blockIdx.y, tid = threadIdx.x;
  int col = colb*128 + tid;
  int f0 = fb*128;
  __shared__ float s_img[32][128];
  for (int r=0;r<32;r++) s_img[r][tid] = img[r*FDIM + f0 + tid];
  __syncthreads();
  float acc[32];
  #pragma unroll
  for (int r=0;r<32;r++) acc[r]=0.f;
  for (int f2=0; f2<128; ++f2){
    float w = Wx[(size_t)(DWW + f0 + f2)*G4 + col];
    #pragma unroll
    for (int r=0;r<32;r++) acc[r] += w * s_img[r][f2];
  }
  #pragma unroll
  for (int r=0;r<32;r++) parts[(size_t)fb*(32*G4) + r*G4 + col] = acc[r];
}

__global__ __launch_bounds__(256) void k_preduce(const float* __restrict__ parts,
                                                 const float* __restrict__ b_lstm,
                                                 float* __restrict__ P)
{
  int i = blockIdx.x*256 + threadIdx.x;
  float s = b_lstm[i & (G4-1)];
  for (int fb=0; fb<16; ++fb) s += parts[(size_t)fb*(32*G4) + i];
  P[i] = s;
}

// ---------------- beam state init ----------------
__global__ __launch_bounds__(512) void k_init(float* h, float* c, float* beam_lp,
                                              int* prev, int* finished, int* lengths, int* ids)
{
  int n = blockIdx.x, m = threadIdx.x;
  h[(size_t)n*HH+m]=0.f; c[(size_t)n*HH+m]=0.f;
  if (m==0){ beam_lp[n] = (n%KW==0)?0.f:NEGV; prev[n]=START_ID; finished[n]=0; lengths[n]=0; }
  if (m<TDEC) ids[n*TDEC+m]=0;
}

// ---------------- LSTM pre-activation GEMM (K-split 8) ----------------
__global__ __launch_bounds__(256) void k_zgemm(
    const float* __restrict__ E, const float* __restrict__ Wx, const float* __restrict__ Wh,
    const float* __restrict__ h, const int* __restrict__ prev, float* __restrict__ zp)
{
  int bx = blockIdx.x, p = blockIdx.y, tid = threadIdx.x;
  int col0 = bx*64;
  int ks = p*104;
  int ke = ks+104 < 812 ? ks+104 : 812;
  __shared__ float sA[96*17];
  __shared__ float sB[16*64];
  int tx = tid & 15, ty = tid >> 4;
  float4 acc[6];
  #pragma unroll
  for (int r=0;r<6;r++) acc[r] = make_float4(0.f,0.f,0.f,0.f);

  for (int k0=ks; k0<ke; k0+=16){
    int bk = ke-k0; if (bk>16) bk=16;
    for (int i=tid; i<96*16; i+=256){
      int n = i>>4, kk = i&15;
      float v = 0.f;
      if (kk < bk){
        int kg = k0 + kk;
        if (kg < DWW){
          int w = prev[n];
          v = E[(size_t)w*DWW + kg];
        } else {
          v = h[(size_t)n*HH + (kg-DWW)];
        }
      }
      sA[n*17+kk] = v;
    }
    for (int i=tid; i<16*64; i+=256){
      int kk = i>>6, cc = i&63;
      float v = 0.f;
      if (kk < bk){
        int kg = k0+kk;
        v = (kg<DWW) ? Wx[(size_t)kg*G4 + col0+cc] : Wh[(size_t)(kg-DWW)*G4 + col0+cc];
      }
      sB[i] = v;
    }
    __syncthreads();
    #pragma unroll
    for (int kk=0; kk<16; ++kk){
      float4 bv = *(const float4*)&sB[kk*64 + tx*4];
      #pragma unroll
      for (int rr=0;rr<6;rr++){
        float a = sA[(ty + rr*16)*17 + kk];
        acc[rr].x += a*bv.x; acc[rr].y += a*bv.y; acc[rr].z += a*bv.z; acc[rr].w += a*bv.w;
      }
    }
    __syncthreads();
  }
  float* zpp = zp + (size_t)p*NK*G4;
  #pragma unroll
  for (int rr=0;rr<6;rr++){
    int row = ty + rr*16;
    *(float4*)&zpp[(size_t)row*G4 + col0 + tx*4] = acc[rr];
  }
}

// ---------------- LSTM cell: reduce 8 partials + P, gates; store h2 per step ------
__global__ __launch_bounds__(512) void k_cell(
    const float* __restrict__ zp, const float* __restrict__ P,
    const float* __restrict__ c,
    float* __restrict__ h2st, float* __restrict__ c2)
{
  int n = blockIdx.x, m = threadIdx.x;
  int bb = n/KW;
  const float* Pr = P + (size_t)bb*G4;
  float zi=Pr[m], zf=Pr[HH+m], zg=Pr[2*HH+m], zo=Pr[3*HH+m];
  for (int p=0;p<8;p++){
    const float* zz = zp + (size_t)p*NK*G4 + (size_t)n*G4;
    zi += zz[m]; zf += zz[HH+m]; zg += zz[2*HH+m]; zo += zz[3*HH+m];
  }
  float cold = c[(size_t)n*HH+m];
  float c2v = sigf(zf+1.0f)*cold + sigf(zi)*tanhf(zg);
  float h2v = sigf(zo)*tanhf(c2v);
  c2[(size_t)n*HH+m]=c2v;
  h2st[(size_t)n*HH+m]=h2v;
}

// ---------------- logits GEMM + fused per-block top3/max/sumexp partials ----------
// grid 188 (64 cols each), block 256. partA[row][blk] = 8 floats
__global__ __launch_bounds__(256) void k_logitsA(
    const float* __restrict__ Hs, const float* __restrict__ Wl,
    const float* __restrict__ blog, float* __restrict__ partA)
{
  int bx = blockIdx.x, tid = threadIdx.x;
  int col0 = bx*64;
  int tx = tid&15, ty = tid>>4;
  __shared__ float sA[96*36];
  __shared__ float sB[32*64];
  float4 acc[6];
  #pragma unroll
  for (int r=0;r<6;r++) acc[r]=make_float4(0.f,0.f,0.f,0.f);

  for (int k0=0;k0<HH;k0+=32){
    for (int i=tid;i<96*8;i+=256){
      int row=i>>3, kq=(i&7)*4;
      *(float4*)&sA[row*36+kq] = *(const float4*)&Hs[(size_t)row*HH + k0 + kq];
    }
    for (int i=tid;i<32*16;i+=256){
      int kk=i>>4, c4=(i&15)*4;
      int col=col0+c4;
      float4 v = make_float4(0.f,0.f,0.f,0.f);
      if (col < VV) v = *(const float4*)&Wl[(size_t)(k0+kk)*VV+col];
      *(float4*)&sB[kk*64+c4] = v;
    }
    __syncthreads();
    #pragma unroll
    for (int kk=0;kk<32;++kk){
      float4 bv = *(const float4*)&sB[kk*64+tx*4];
      #pragma unroll
      for (int rr=0;rr<6;rr++){
        float a = sA[(ty+rr*16)*36+kk];
        acc[rr].x += a*bv.x; acc[rr].y += a*bv.y; acc[rr].z += a*bv.z; acc[rr].w += a*bv.w;
      }
    }
    __syncthreads();
  }

  int colg = col0 + tx*4;
  bool cval = colg < VV;          // all-or-none per float4 (VV%4==0)
  float4 bias = make_float4(0.f,0.f,0.f,0.f);
  if (cval) bias = *(const float4*)&blog[colg];

  #pragma unroll
  for (int rr=0;rr<6;rr++){
    int row = ty + rr*16;
    float v0,v1,v2,v3;
    if (cval){
      v0 = acc[rr].x + bias.x; v1 = acc[rr].y + bias.y;
      v2 = acc[rr].z + bias.z; v3 = acc[rr].w + bias.w;
    } else { v0=v1=v2=v3=-INFINITY; }
    // row max over 64 cols (16 tx lanes)
    float m = fmaxf(fmaxf(v0,v1), fmaxf(v2,v3));
    #pragma unroll
    for (int d=1;d<16;d<<=1) m = fmaxf(m, __shfl_xor(m,d));
    // top3 (global col indices)
    float tv[3]={-INFINITY,-INFINITY,-INFINITY};
    int   ti[3]={INTMX,INTMX,INTMX};
    if (cval){
      ins3(v0,colg,tv,ti); ins3(v1,colg+1,tv,ti);
      ins3(v2,colg+2,tv,ti); ins3(v3,colg+3,tv,ti);
    }
    // sumexp relative to block-local row max
    float s = 0.f;
    if (cval){
      s = expf(v0-m)+expf(v1-m)+expf(v2-m)+expf(v3-m);
    }
    #pragma unroll
    for (int d=1;d<16;d<<=1){
      s += __shfl_xor(s,d);
      float p0=__shfl_xor(tv[0],d), p1=__shfl_xor(tv[1],d), p2=__shfl_xor(tv[2],d);
      int   q0=__shfl_xor(ti[0],d), q1=__shfl_xor(ti[1],d), q2=__shfl_xor(ti[2],d);
      ins3(p0,q0,tv,ti); ins3(p1,q1,tv,ti); ins3(p2,q2,tv,ti);
    }
    if (tx==0){
      float* rp = partA + ((size_t)row*NLB + bx)*8;
      float4 r0 = make_float4(m, s, tv[0], tv[1]);
      float4 r1 = make_float4(tv[2], __int_as_float(ti[0]), __int_as_float(ti[1]), __int_as_float(ti[2]));
      *(float4*)rp = r0;
      *((float4*)rp+1) = r1;
    }
  }
}

// ---------------- beam select: merge 188 records/beam, combine, reorder -----------
__global__ __launch_bounds__(256) void k_selectB(
    const float* __restrict__ partA, const float* __restrict__ Hs,
    const float* __restrict__ c2,
    float* __restrict__ h, float* __restrict__ c,
    float* __restrict__ beam_lp, int* __restrict__ prev,
    int* __restrict__ finished, int* __restrict__ lengths,
    int* __restrict__ ids, int* __restrict__ parst, int t)
{
  int b = blockIdx.x, tid = threadIdx.x;
  int lane = tid & 63, wid = tid >> 6;
  __shared__ float s_m[4], s_s[4], s_tv[4][3];
  __shared__ int   s_ti[4][3];
  __shared__ float s_lse[KW], s_topv[KW][3];
  __shared__ int   s_topi[KW][3];
  __shared__ int   s_par[KW], s_word[KW];
  __shared__ int   s_idsb[KW][TDEC];

  for (int k=0;k<KW;k++){
    int n = b*KW+k;
    float m_t = -INFINITY, sum_t = 0.f;
    float tv[3]={-INFINITY,-INFINITY,-INFINITY};
    int   ti[3]={INTMX,INTMX,INTMX};
    if (tid < NLB){
      const float* rp = partA + ((size_t)n*NLB + tid)*8;
      float4 r0 = *(const float4*)rp;
      float4 r1 = *((const float4*)rp+1);
      m_t = r0.x; sum_t = r0.y;
      tv[0]=r0.z; tv[1]=r0.w; tv[2]=r1.x;
      ti[0]=__float_as_int(r1.y); ti[1]=__float_as_int(r1.z); ti[2]=__float_as_int(r1.w);
    }
    float M = m_t;
    #pragma unroll
    for (int d=1;d<64;d<<=1) M = fmaxf(M, __shfl_xor(M,d));
    if (lane==0) s_m[wid]=M;
    __syncthreads();
    float Mg = fmaxf(fmaxf(s_m[0],s_m[1]),fmaxf(s_m[2],s_m[3]));
    float sc = (tid<NLB) ? sum_t * expf(m_t - Mg) : 0.f;
    #pragma unroll
    for (int d=1;d<64;d<<=1){
      sc += __shfl_xor(sc,d);
      float p0=__shfl_xor(tv[0],d), p1=__shfl_xor(tv[1],d), p2=__shfl_xor(tv[2],d);
      int   q0=__shfl_xor(ti[0],d), q1=__shfl_xor(ti[1],d), q2=__shfl_xor(ti[2],d);
      ins3(p0,q0,tv,ti); ins3(p1,q1,tv,ti); ins3(p2,q2,tv,ti);
    }
    if (lane==0){
      s_s[wid]=sc;
      s_tv[wid][0]=tv[0]; s_tv[wid][1]=tv[1]; s_tv[wid][2]=tv[2];
      s_ti[wid][0]=ti[0]; s_ti[wid][1]=ti[1]; s_ti[wid][2]=ti[2];
    }
    __syncthreads();
    if (tid==0){
      float S = s_s[0]+s_s[1]+s_s[2]+s_s[3];
      float mv[3]={-INFINITY,-INFINITY,-INFINITY};
      int   mi[3]={INTMX,INTMX,INTMX};
      for (int w2=0;w2<4;w2++)
        for (int j=0;j<3;j++) ins3(s_tv[w2][j], s_ti[w2][j], mv, mi);
      s_lse[k] = Mg + logf(S);
      for (int j=0;j<3;j++){ s_topv[k][j]=mv[j]; s_topi[k][j]=mi[j]; }
    }
    __syncthreads();
  }

  if (tid==0){
    float cv[3]={-INFINITY,-INFINITY,-INFINITY};
    int   cf[3]={INTMX,INTMX,INTMX};
    for (int k=0;k<KW;k++){
      int n=b*KW+k;
      if (finished[n]){
        ins3(beam_lp[n], k*VV+END_ID, cv, cf);
      } else {
        float blp = beam_lp[n], lse = s_lse[k];
        for (int j=0;j<3;j++)
          ins3(blp + (s_topv[k][j] - lse), k*VV + s_topi[k][j], cv, cf);
      }
    }
    int fin_old[KW], len_old[KW];
    for (int j=0;j<KW;j++){ fin_old[j]=finished[b*KW+j]; len_old[j]=lengths[b*KW+j]; }
    for (int kp=0;kp<KW;kp++){
      int par = cf[kp]/VV, word = cf[kp]-par*VV;
      s_par[kp]=par; s_word[kp]=word;
      beam_lp[b*KW+kp]=cv[kp];
      prev[b*KW+kp]=word;
      parst[b*KW+kp]=b*KW+par;
      int fp = fin_old[par];
      lengths[b*KW+kp] = fp ? len_old[par] : (len_old[par]+1);
      finished[b*KW+kp] = fp | (word==END_ID);
    }
  }
  __syncthreads();
  for (int i=tid;i<KW*HH;i+=256){
    int slot=i>>9, m=i&(HH-1);
    h[(size_t)(b*KW+slot)*HH+m] = Hs[(size_t)(b*KW+s_par[slot])*HH+m];
    c[(size_t)(b*KW+slot)*HH+m] = c2[(size_t)(b*KW+s_par[slot])*HH+m];
  }
  if (tid < KW*TDEC){
    int slot=tid>>5, tt=tid&(TDEC-1);
    s_idsb[slot][tt] = ids[(b*KW+s_par[slot])*TDEC+tt];
  }
  __syncthreads();
  if (tid < KW*TDEC){
    int slot=tid>>5, tt=tid&(TDEC-1);
    ids[(b*KW+slot)*TDEC+tt] = (tt==t) ? s_word[slot] : s_idsb[slot][tt];
  }
}

// ---------------- backtrack ancestors -> rowsrc map ----------------
__global__ __launch_bounds__(128) void k_backtrack(const int* __restrict__ parst,
                                                   const int* __restrict__ lengths,
                                                   int* __restrict__ rowsrc)
{
  int n = threadIdx.x;
  if (n >= NK) return;
  int b = n / KW;
  int len = lengths[n];
  rowsrc[n*SEQ + TDEC] = -1;                 // tau = 32 always inactive (len <= 32)
  int a = n;                                  // A_31
  for (int tau = TDEC-1; tau >= 1; --tau){
    int p = parst[tau*NK + a];                // A_{tau-1}
    rowsrc[n*SEQ + tau] = (tau < len) ? (tau*NK + p) : -1;
    a = p;
  }
  rowsrc[n*SEQ + 0] = b*KW;                   // h2_0 identical within batch; len >= 1
}

// ---------------- final logits GEMM + bias + argmax partials ----------------
// grid (25 rowblk x 94 colblk), block 256; BM=128,BN=128,Kc=16; dbuf reg->LDS
__global__ __launch_bounds__(256) void k_final(
    const float* __restrict__ h2s, const int* __restrict__ rowsrc,
    const float* __restrict__ Wl, const float* __restrict__ blog,
    float* __restrict__ out, float* __restrict__ argp)
{
  int bx=blockIdx.x, by=blockIdx.y, tid=threadIdx.x;
  int row0 = bx*128, col0 = by*128;
  int tx = tid & 31, ty = tid >> 5;
  int colg = col0 + tx*4;
  bool cval = colg < VV;

  __shared__ float sA[2][16*132];
  __shared__ float sB[2][16*128];
  __shared__ int s_src[128];
  for (int i=tid;i<128;i+=256){
    int r=row0+i;
    s_src[i] = (r<NROWS) ? rowsrc[r] : -1;
  }
  __syncthreads();

  int arow = tid>>1;
  int akq  = (tid&1)*8;
  int bkk  = tid>>5;
  int bcc  = (tid&31)*4;
  int asrc = s_src[arow];
  const float* abase = (asrc>=0) ? (h2s + (size_t)asrc*HH) : (const float*)0;
  bool bval = (col0 + bcc) < VV;
  const float* bbase = Wl + (size_t)bkk*VV + col0 + bcc;

  float4 acc[16];
  #pragma unroll
  for (int r=0;r<16;r++) acc[r]=make_float4(0.f,0.f,0.f,0.f);

  float4 a0,a1,b0,b1;
  // preload chunk 0
  {
    if (abase){ a0 = *(const float4*)(abase + akq); a1 = *(const float4*)(abase + akq + 4); }
    else { a0=a1=make_float4(0.f,0.f,0.f,0.f); }
    if (bval){ b0 = *(const float4*)(bbase); b1 = *(const float4*)(bbase + (size_t)8*VV); }
    else { b0=b1=make_float4(0.f,0.f,0.f,0.f); }
  }
  // write chunk 0
  {
    float* sAc = &sA[0][0]; float* sBc = &sB[0][0];
    sAc[(akq+0)*132+arow]=a0.x; sAc[(akq+1)*132+arow]=a0.y;
    sAc[(akq+2)*132+arow]=a0.z; sAc[(akq+3)*132+arow]=a0.w;
    sAc[(akq+4)*132+arow]=a1.x; sAc[(akq+5)*132+arow]=a1.y;
    sAc[(akq+6)*132+arow]=a1.z; sAc[(akq+7)*132+arow]=a1.w;
    *(float4*)&sBc[bkk*128+bcc] = b0;
    *(float4*)&sBc[(bkk+8)*128+bcc] = b1;
  }

  int buf = 0;
  for (int ch=0; ch<32; ++ch){
    __syncthreads();
    if (ch < 31){
      int k0 = (ch+1)*16;
      if (abase){ a0 = *(const float4*)(abase + k0 + akq); a1 = *(const float4*)(abase + k0 + akq + 4); }
      if (bval){ b0 = *(const float4*)(bbase + (size_t)k0*VV); b1 = *(const float4*)(bbase + (size_t)(k0+8)*VV); }
    }
    const float* sAc = &sA[buf][0];
    const float* sBc = &sB[buf][0];
    #pragma unroll
    for (int kk=0;kk<16;++kk){
      float4 b4 = *(const float4*)&sBc[kk*128 + tx*4];
      #pragma unroll
      for (int rr=0;rr<4;rr++){
        float4 a4 = *(const float4*)&sAc[kk*132 + ty*16 + rr*4];
        float4* A0 = &acc[rr*4+0]; float4* A1 = &acc[rr*4+1];
        float4* A2 = &acc[rr*4+2]; float4* A3 = &acc[rr*4+3];
        A0->x += a4.x*b4.x; A0->y += a4.x*b4.y; A0->z += a4.x*b4.z; A0->w += a4.x*b4.w;
        A1->x += a4.y*b4.x; A1->y += a4.y*b4.y; A1->z += a4.y*b4.z; A1->w += a4.y*b4.w;
        A2->x += a4.z*b4.x; A2->y += a4.z*b4.y; A2->z += a4.z*b4.z; A2->w += a4.z*b4.w;
        A3->x += a4.w*b4.x; A3->y += a4.w*b4.y; A3->z += a4.w*b4.z; A3->w += a4.w*b4.w;
      }
    }
    if (ch < 31){
      float* sAn = &sA[buf^1][0]; float* sBn = &sB[buf^1][0];
      sAn[(akq+0)*132+arow]=a0.x; sAn[(akq+1)*132+arow]=a0.y;
      sAn[(akq+2)*132+arow]=a0.z; sAn[(akq+3)*132+arow]=a0.w;
      sAn[(akq+4)*132+arow]=a1.x; sAn[(akq+5)*132+arow]=a1.y;
      sAn[(akq+6)*132+arow]=a1.z; sAn[(akq+7)*132+arow]=a1.w;
      *(float4*)&sBn[bkk*128+bcc] = b0;
      *(float4*)&sBn[(bkk+8)*128+bcc] = b1;
      buf ^= 1;
    }
  }

  float4 bias = make_float4(0.f,0.f,0.f,0.f);
  if (cval) bias = *(const float4*)&blog[colg];
  #pragma unroll
  for (int i=0;i<16;i++){
    int row = row0 + ty*16 + i;
    float4 v = acc[i];
    v.x += bias.x; v.y += bias.y; v.z += bias.z; v.w += bias.w;
    float bv = -INFINITY; int bi = INTMX;
    if (cval){
      if (row < NROWS) nt_store4(out + (size_t)row*VV + colg, v);
      bv = v.x; bi = colg;
      if (v.y > bv){ bv=v.y; bi=colg+1; }
      if (v.z > bv){ bv=v.z; bi=colg+2; }
      if (v.w > bv){ bv=v.w; bi=colg+3; }
    }
    #pragma unroll
    for (int d=1;d<32;d<<=1){
      float ov = __shfl_xor(bv,d); int oi = __shfl_xor(bi,d);
      if (ov > bv || (ov == bv && oi < bi)){ bv=ov; bi=oi; }
    }
    if (tx==0 && row < NROWS){
      argp[((size_t)row*NCB + by)*2]   = bv;
      argp[((size_t)row*NCB + by)*2+1] = __int_as_float(bi);
    }
  }
}

// grid 396 x 256: 8 rows/block, 32 lanes/row reduce 94 partials
__global__ __launch_bounds__(256) void k_amax(const float* __restrict__ argp,
                                              float* __restrict__ outb)
{
  int tid = threadIdx.x;
  int row = blockIdx.x*8 + (tid>>5);
  int lane = tid & 31;
  if (row >= NROWS) return;
  float bv = -INFINITY; int bi = INTMX;
  for (int p=lane; p<NCB; p+=32){
    float v = argp[((size_t)row*NCB+p)*2];
    int  i2 = __float_as_int(argp[((size_t)row*NCB+p)*2+1]);
    if (v > bv || (v == bv && i2 < bi)){ bv=v; bi=i2; }
  }
  #pragma unroll
  for (int d=1;d<32;d<<=1){
    float ov = __shfl_xor(bv,d); int oi = __shfl_xor(bi,d);
    if (ov > bv || (ov == bv && oi < bi)){ bv=ov; bi=oi; }
  }
  if (lane==0) outb[row] = (float)bi;
}

extern "C" void kernel_launch(void* const* d_in, const int* in_sizes, int n_in,
                              void* d_out, int out_size, void* d_ws, size_t ws_size,
                              hipStream_t stream) {
  (void)in_sizes; (void)n_in; (void)out_size; (void)ws_size;
  const float* img  = (const float*)d_in[0];
  const float* E    = (const float*)d_in[1];
  const float* Wx   = (const float*)d_in[2];
  const float* Wh   = (const float*)d_in[3];
  const float* bls  = (const float*)d_in[4];
  const float* Wl   = (const float*)d_in[5];
  const float* blog = (const float*)d_in[6];
  float* out = (float*)d_out;

  float* ws = (float*)d_ws;
  size_t o = 0;
  float* P     = ws + o; o += (size_t)NB*G4;            // 65536
  float* h     = ws + o; o += (size_t)NK*HH;            // 49152
  float* c     = ws + o; o += (size_t)NK*HH;
  float* c2    = ws + o; o += (size_t)NK*HH;
  float* h2s   = ws + o; o += (size_t)TDEC*NK*HH;       // per-step h2 store
  float* partA = ws + o; o += (size_t)NK*NLB*8;
  float* zpL   = ws + o; o += (size_t)8*NK*G4;          // also aliased by k_pimg parts
  float* argp  = ws + o; o += (size_t)NROWS*NCB*2;
  float* beam_lp = ws + o; o += 128;
  int* prev     = (int*)(ws + o); o += 128;
  int* finished = (int*)(ws + o); o += 128;
  int* lengths  = (int*)(ws + o); o += 128;
  int* ids      = (int*)(ws + o); o += NK*TDEC;
  int* parst    = (int*)(ws + o); o += TDEC*NK;
  int* rowsrc   = (int*)(ws + o); o += 3200;
  float* parts  = zpL;

  // precompute P = b_lstm + img @ Wx[300:,:]
  k_pimg<<<dim3(16,16),128,0,stream>>>(img, Wx, parts);
  k_preduce<<<256,256,0,stream>>>(parts, bls, P);
  k_init<<<NK,HH,0,stream>>>(h,c,beam_lp,prev,finished,lengths,ids);

  // beam-search decode (h2 archived per step; teacher phase eliminated via backtrack)
  for (int t=0;t<TDEC;t++){
    float* Hs = h2s + (size_t)t*NK*HH;
    k_zgemm<<<dim3(32,8),256,0,stream>>>(E,Wx,Wh,h,prev,zpL);
    k_cell<<<NK,HH,0,stream>>>(zpL,P,c,Hs,c2);
    k_logitsA<<<NLB,256,0,stream>>>(Hs,Wl,blog,partA);
    k_selectB<<<NB,256,0,stream>>>(partA,Hs,c2,h,c,beam_lp,prev,finished,lengths,ids,
                                   parst + (size_t)t*NK, t);
  }

  k_backtrack<<<1,128,0,stream>>>(parst, lengths, rowsrc);

  // final logits + argmax
  k_final<<<dim3(25,NCB),256,0,stream>>>(h2s, rowsrc, Wl, blog, out, argp);
  k_amax<<<396,256,0,stream>>>(argp, out + (size_t)NROWS*VV);
}